// Round 4
// baseline (23309.683 us; speedup 1.0000x reference)
//
#include <hip/hip_runtime.h>

// RNN echo-state scan on MI355X — round 4.
// Protocol = round 2's PROVEN one: sc1 write-through publish -> syncthreads
// (vmcnt drain) -> flag post; consumer poll + acquire-fence (buffer_inv).
// New vs r2: per-wave poll/fence (no consumer barrier), and the A-tile
// exchange loads are issued ALL AT ONCE into registers (64x16B per wave,
// sched_barrier-pinned) so we pay ~1 miss latency, not 16 serialized ones
// (r2 had VGPR_Count=56 -> compiler serialized the misses; ~9us/step).

#define TT    2048
#define BB    64
#define NIN   64
#define NRECN 1024
#define KTOT  1088
#define MT    32
#define NT    32
#define NGRP  2
#define WPG   32
#define NWG   (NGRP * WPG)
#define NOISE_STD 0.001f

typedef __attribute__((ext_vector_type(8))) short short8;
typedef __attribute__((ext_vector_type(4))) float f32x4;

__device__ __forceinline__ unsigned short f2bf(float f) {
  unsigned u = __float_as_uint(f);
  u += 0x7FFFu + ((u >> 16) & 1u);   // RNE to bf16
  return (unsigned short)(u >> 16);
}
__device__ __forceinline__ float bf2f(unsigned short h) {
  return __uint_as_float(((unsigned)h) << 16);
}
// Write-through, agent-coherent 2B store (reaches coherence point; proven r2).
__device__ __forceinline__ void st_b16_sc1(unsigned short* p, unsigned short v) {
  unsigned vv = v;
  asm volatile("global_store_short %0, %1, off sc1" :: "v"(p), "v"(vv) : "memory");
}
__device__ __forceinline__ void split8(const f32x4& v0, const f32x4& v1,
                                       short8& ah, short8& al) {
  #pragma unroll
  for (int j = 0; j < 4; ++j) {
    unsigned short h = f2bf(v0[j]);
    ah[j] = (short)h; al[j] = (short)f2bf(v0[j] - bf2f(h));
  }
  #pragma unroll
  for (int j = 0; j < 4; ++j) {
    unsigned short h = f2bf(v1[j]);
    ah[4 + j] = (short)h; al[4 + j] = (short)f2bf(v1[j] - bf2f(h));
  }
}

__global__ __launch_bounds__(256, 1) void rnn_scan_kernel(
    const float* __restrict__ x, const float* __restrict__ W_ih,
    const float* __restrict__ W_hh, const float* __restrict__ noise,
    float* __restrict__ out, int* __restrict__ flags,
    unsigned short* __restrict__ th_hi, unsigned short* __restrict__ th_lo)
{
  extern __shared__ unsigned short smem[];
  unsigned short* w_hi = smem;                      // chunk-major [KTOT/8][NT][8]
  unsigned short* w_lo = smem + KTOT * NT;

  const int wg = blockIdx.x, gm = wg / WPG, gn = wg % WPG;
  const int tid = threadIdx.x, lane = tid & 63, wv = tid >> 6;
  const int msub = wv >> 1, nsub = wv & 1;
  const int l15 = lane & 15, g4 = lane >> 4, lk8 = g4 * 8;

  // one-time: W slice -> LDS, hi/lo bf16, layout idx = (k>>3)*256 + row*8 + (k&7)
  for (int idx = tid; idx < NT * KTOT; idx += 256) {
    int nr = idx / KTOT, k = idx - nr * KTOT;
    int ng = gn * NT + nr;
    float v = (k < NRECN) ? W_hh[(size_t)ng * NRECN + k]
                          : W_ih[(size_t)ng * NIN + (k - NRECN)];
    unsigned short h = f2bf(v);
    unsigned short l = f2bf(v - bf2f(h));
    int widx = (k >> 3) * (NT * 8) + nr * 8 + (k & 7);
    w_hi[widx] = h; w_lo[widx] = l;
  }
  __syncthreads();

  int* flags_g = flags + gm * 64;                   // groups 256B apart
  const int mloc = msub * 16 + l15;
  const int nloc = nsub * 16 + l15;
  const int b_glob = gm * MT + mloc;
  const int n_glob = gn * NT + nloc;
  const unsigned short* whp = w_hi + g4 * 256 + nloc * 8;  // + c*1024 per chunk
  const unsigned short* wlp = w_lo + g4 * 256 + nloc * 8;
  const int grp_off = gm * 2 * MT * NRECN;
  const float* xrow = x + (size_t)b_glob * TT * NIN;

  f32x4 xv0, xv1, xv2, xv3;
  f32x4 xn0 = {0,0,0,0}, xn1 = {0,0,0,0}, xn2 = {0,0,0,0}, xn3 = {0,0,0,0};
  { const float* xp = xrow + lk8;
    xv0 = *(const f32x4*)xp;        xv1 = *(const f32x4*)(xp + 4);
    xv2 = *(const f32x4*)(xp + 32); xv3 = *(const f32x4*)(xp + 36); }
  float nzv = noise[n_glob] * NOISE_STD, nzn = 0.f;

  for (int t = 0; t < TT; ++t) {
    const int buf = t & 1;

    f32x4 h0 = {0,0,0,0}, h1 = {0,0,0,0}, l0 = {0,0,0,0},
          l1 = {0,0,0,0}, m0 = {0,0,0,0}, m1 = {0,0,0,0};

    // ---- x part (chunks 32,33) — regs+LDS only; overlaps the poll below
    {
      short8 ah, al;
      split8(xv0, xv1, ah, al);
      short8 bh = *(const short8*)(whp + 32 * 1024);
      short8 bl = *(const short8*)(wlp + 32 * 1024);
      h0 = __builtin_amdgcn_mfma_f32_16x16x32_bf16(ah, bh, h0, 0, 0, 0);
      l0 = __builtin_amdgcn_mfma_f32_16x16x32_bf16(al, bh, l0, 0, 0, 0);
      m0 = __builtin_amdgcn_mfma_f32_16x16x32_bf16(ah, bl, m0, 0, 0, 0);
      split8(xv2, xv3, ah, al);
      bh = *(const short8*)(whp + 33 * 1024);
      bl = *(const short8*)(wlp + 33 * 1024);
      h1 = __builtin_amdgcn_mfma_f32_16x16x32_bf16(ah, bh, h1, 0, 0, 0);
      l1 = __builtin_amdgcn_mfma_f32_16x16x32_bf16(al, bh, l1, 0, 0, 0);
      m1 = __builtin_amdgcn_mfma_f32_16x16x32_bf16(ah, bl, m1, 0, 0, 0);
    }

    // ---- recurrent part
    if (t > 0) {
      // every wave polls independently, then acquire-invs (proven r2 protocol,
      // minus the consumer barrier: each wave proceeds the moment it sees t)
      if (lane < WPG) {
        while (__hip_atomic_load(&flags_g[lane], __ATOMIC_RELAXED,
                                 __HIP_MEMORY_SCOPE_AGENT) < t) { }
      }
      __builtin_amdgcn_fence(__ATOMIC_ACQUIRE, "agent");  // buffer_inv

      const unsigned short* ah_p =
          th_hi + grp_off + buf * MT * NRECN + mloc * NRECN + lk8;
      const unsigned short* al_p =
          th_lo + grp_off + buf * MT * NRECN + mloc * NRECN + lk8;

      // issue ALL 64 exchange loads into registers, THEN compute.
      short8 A[32], L[32];
      #pragma unroll
      for (int c = 0; c < 32; ++c) {
        A[c] = *(const short8*)(ah_p + c * 32);
        L[c] = *(const short8*)(al_p + c * 32);
      }
      __builtin_amdgcn_sched_barrier(0);   // loads stay above, MFMAs below

      #pragma unroll
      for (int c = 0; c < 32; c += 2) {
        short8 b0h = *(const short8*)(whp + c * 1024);
        short8 b0l = *(const short8*)(wlp + c * 1024);
        h0 = __builtin_amdgcn_mfma_f32_16x16x32_bf16(A[c], b0h, h0, 0, 0, 0);
        l0 = __builtin_amdgcn_mfma_f32_16x16x32_bf16(L[c], b0h, l0, 0, 0, 0);
        m0 = __builtin_amdgcn_mfma_f32_16x16x32_bf16(A[c], b0l, m0, 0, 0, 0);
        short8 b1h = *(const short8*)(whp + (c + 1) * 1024);
        short8 b1l = *(const short8*)(wlp + (c + 1) * 1024);
        h1 = __builtin_amdgcn_mfma_f32_16x16x32_bf16(A[c+1], b1h, h1, 0, 0, 0);
        l1 = __builtin_amdgcn_mfma_f32_16x16x32_bf16(L[c+1], b1h, l1, 0, 0, 0);
        m1 = __builtin_amdgcn_mfma_f32_16x16x32_bf16(A[c+1], b1l, m1, 0, 0, 0);
      }
    }

    // ---- epilogue: h, tanh, split, write-through publish
    f32x4 hs = ((h0 + h1) + (l0 + l1)) + (m0 + m1);
    const int nbuf = (t + 1) & 1;
    unsigned short* oh = th_hi + grp_off + nbuf * MT * NRECN;
    unsigned short* ol = th_lo + grp_off + nbuf * MT * NRECN;
    float hout[4];
    #pragma unroll
    for (int r = 0; r < 4; ++r) {
      const int mr = msub * 16 + g4 * 4 + r;       // C-frag row (m89 layout)
      float h = hs[r] + nzv;
      hout[r] = h;
      float e  = __expf(2.f * h);
      float th = 1.f - 2.f / (e + 1.f);
      unsigned short hh = f2bf(th);
      unsigned short hl = f2bf(th - bf2f(hh));
      st_b16_sc1(oh + mr * NRECN + n_glob, hh);
      st_b16_sc1(ol + mr * NRECN + n_glob, hl);
    }
    __syncthreads();   // drains vmcnt(0) in every wave -> th visible (proven r2)
    if (tid == 0)
      __hip_atomic_store(&flags_g[gn], t + 1, __ATOMIC_RELAXED,
                         __HIP_MEMORY_SCOPE_AGENT);

    // ---- prefetch x/noise for t+1 (off critical path)
    if (t + 1 < TT) {
      const float* xp = xrow + (size_t)(t + 1) * NIN + lk8;
      xn0 = *(const f32x4*)xp;        xn1 = *(const f32x4*)(xp + 4);
      xn2 = *(const f32x4*)(xp + 32); xn3 = *(const f32x4*)(xp + 36);
      nzn = noise[(size_t)(t + 1) * NRECN + n_glob] * NOISE_STD;
    }

    // ---- outputs (off the critical path, after flag post)
    #pragma unroll
    for (int r = 0; r < 4; ++r) {
      const int mr = msub * 16 + g4 * 4 + r;
      const int br = gm * MT + mr;
      if (br == BB - 1) out[(size_t)n_glob * TT + t] = hout[r];
      if (t == TT - 1)
        out[(size_t)NRECN * TT + (size_t)br * NRECN + n_glob] = hout[r];
    }
    xv0 = xn0; xv1 = xn1; xv2 = xn2; xv3 = xn3; nzv = nzn;
  }
}

extern "C" void kernel_launch(void* const* d_in, const int* in_sizes, int n_in,
                              void* d_out, int out_size, void* d_ws, size_t ws_size,
                              hipStream_t stream) {
  const float* x     = (const float*)d_in[0];
  const float* W_ih  = (const float*)d_in[1];
  const float* W_hh  = (const float*)d_in[2];
  const float* noise = (const float*)d_in[3];
  float* out = (float*)d_out;

  char* ws = (char*)d_ws;
  int* flags = (int*)ws;                                   // 2 groups, 256B apart
  unsigned short* th_hi = (unsigned short*)(ws + 1024);    // [2][2][32][1024] bf16
  unsigned short* th_lo = th_hi + NGRP * 2 * MT * NRECN;
  // ws usage: 1024 + 2*262144 = 525,312 bytes

  (void)hipMemsetAsync(flags, 0, 1024, stream);            // deterministic replays

  const size_t lds_bytes = (size_t)2 * KTOT * NT * sizeof(unsigned short); // 139,264
  (void)hipFuncSetAttribute((const void*)rnn_scan_kernel,
                            hipFuncAttributeMaxDynamicSharedMemorySize,
                            (int)lds_bytes);

  rnn_scan_kernel<<<dim3(NWG), dim3(256), lds_bytes, stream>>>(
      x, W_ih, W_hh, noise, out, flags, th_hi, th_lo);
}

// Round 6
// 12479.579 us; speedup vs baseline: 1.8678x; 1.8678x over previous
//
#include <hip/hip_runtime.h>

// RNN echo-state scan on MI355X — round 6 (r5 with the 13-bit-offset fix).
// Protocol: sc1 write-through publish -> per-wave vmcnt(0) drain -> per-WG flag
// counter (atomic add, 4/step); consumer poll (all waves) + acquire-inv.
// tanh(h) published as SINGLE bf16 plane (W stays hi/lo, x stays hi/lo).
// A-batch: 32 x 16B inline-asm loads, 16 base ptrs x imm offsets {0,2048}
// (global_load imm offset is 13-bit SIGNED -> max 4095; r5 used 4096/6144).

#define TT    2048
#define BB    64
#define NIN   64
#define NRECN 1024
#define KTOT  1088
#define MT    32
#define NT    32
#define NGRP  2
#define WPG   32
#define NWG   (NGRP * WPG)
#define NOISE_STD 0.001f

typedef __attribute__((ext_vector_type(8))) short short8;
typedef __attribute__((ext_vector_type(4))) float f32x4;

__device__ __forceinline__ unsigned short f2bf(float f) {
  unsigned u = __float_as_uint(f);
  u += 0x7FFFu + ((u >> 16) & 1u);   // RNE to bf16
  return (unsigned short)(u >> 16);
}
__device__ __forceinline__ float bf2f(unsigned short h) {
  return __uint_as_float(((unsigned)h) << 16);
}
// Write-through, agent-coherent 2B store (proven r2/r4).
__device__ __forceinline__ void st_b16_sc1(unsigned short* p, unsigned short v) {
  unsigned vv = v;
  asm volatile("global_store_short %0, %1, off sc1" :: "v"(p), "v"(vv) : "memory");
}
__device__ __forceinline__ void split8(const f32x4& v0, const f32x4& v1,
                                       short8& ah, short8& al) {
  #pragma unroll
  for (int j = 0; j < 4; ++j) {
    unsigned short h = f2bf(v0[j]);
    ah[j] = (short)h; al[j] = (short)f2bf(v0[j] - bf2f(h));
  }
  #pragma unroll
  for (int j = 0; j < 4; ++j) {
    unsigned short h = f2bf(v1[j]);
    ah[4 + j] = (short)h; al[4 + j] = (short)f2bf(v1[j] - bf2f(h));
  }
}

// Batched 16B load, immediate offset (MUST be -4096..4095).
#define LDA16(V, P, OFF) \
  asm volatile("global_load_dwordx4 %0, %1, off offset:%c2" \
               : "=&v"(V) : "v"(P), "n"(OFF))

__global__ __launch_bounds__(256, 1) void rnn_scan_kernel(
    const float* __restrict__ x, const float* __restrict__ W_ih,
    const float* __restrict__ W_hh, const float* __restrict__ noise,
    float* __restrict__ out, int* __restrict__ flags,
    unsigned short* __restrict__ th)
{
  extern __shared__ unsigned short smem[];
  unsigned short* w_hi = smem;                      // chunk-major [KTOT/8][NT][8]
  unsigned short* w_lo = smem + KTOT * NT;

  const int wg = blockIdx.x, gm = wg / WPG, gn = wg % WPG;
  const int tid = threadIdx.x, lane = tid & 63, wv = tid >> 6;
  const int msub = wv >> 1, nsub = wv & 1;
  const int l15 = lane & 15, g4 = lane >> 4, lk8 = g4 * 8;

  // one-time: W slice -> LDS, hi/lo bf16, layout idx = (k>>3)*256 + row*8 + (k&7)
  for (int idx = tid; idx < NT * KTOT; idx += 256) {
    int nr = idx / KTOT, k = idx - nr * KTOT;
    int ng = gn * NT + nr;
    float v = (k < NRECN) ? W_hh[(size_t)ng * NRECN + k]
                          : W_ih[(size_t)ng * NIN + (k - NRECN)];
    unsigned short h = f2bf(v);
    unsigned short l = f2bf(v - bf2f(h));
    int widx = (k >> 3) * (NT * 8) + nr * 8 + (k & 7);
    w_hi[widx] = h; w_lo[widx] = l;
  }
  __syncthreads();

  int* flags_g = flags + gm * WPG * 16;             // one flag per 64B
  const int mloc = msub * 16 + l15;                 // batch row (A)
  const int nloc = nsub * 16 + l15;                 // local out col (B row)
  const int b_glob = gm * MT + mloc;
  const int n_glob = gn * NT + nloc;
  const unsigned short* whp = w_hi + g4 * 256 + nloc * 8;  // + c*1024 per chunk
  const unsigned short* wlp = w_lo + g4 * 256 + nloc * 8;
  const int grp_th = gm * (2 * WPG * MT * NT);      // th: [grp][buf][blk][b][32]
  const float* xrow = x + (size_t)b_glob * TT * NIN;

  f32x4 xv0, xv1, xv2, xv3;
  f32x4 xn0 = {0,0,0,0}, xn1 = {0,0,0,0}, xn2 = {0,0,0,0}, xn3 = {0,0,0,0};
  { const float* xp = xrow + lk8;
    xv0 = *(const f32x4*)xp;        xv1 = *(const f32x4*)(xp + 4);
    xv2 = *(const f32x4*)(xp + 32); xv3 = *(const f32x4*)(xp + 36); }
  float nzv = noise[n_glob] * NOISE_STD, nzn = 0.f;

  for (int t = 0; t < TT; ++t) {
    const int buf = t & 1;

    f32x4 p0 = {0,0,0,0}, p1 = {0,0,0,0}, q0 = {0,0,0,0}, q1 = {0,0,0,0};

    // ---- x part (chunks 32,33), hi/lo split kept — overlaps the poll below
    {
      short8 ah, al;
      split8(xv0, xv1, ah, al);
      short8 bh = *(const short8*)(whp + 32 * 1024);
      short8 bl = *(const short8*)(wlp + 32 * 1024);
      p0 = __builtin_amdgcn_mfma_f32_16x16x32_bf16(ah, bh, p0, 0, 0, 0);
      q0 = __builtin_amdgcn_mfma_f32_16x16x32_bf16(ah, bl, q0, 0, 0, 0);
      p1 = __builtin_amdgcn_mfma_f32_16x16x32_bf16(al, bh, p1, 0, 0, 0);
      split8(xv2, xv3, ah, al);
      bh = *(const short8*)(whp + 33 * 1024);
      bl = *(const short8*)(wlp + 33 * 1024);
      p1 = __builtin_amdgcn_mfma_f32_16x16x32_bf16(ah, bh, p1, 0, 0, 0);
      q1 = __builtin_amdgcn_mfma_f32_16x16x32_bf16(ah, bl, q1, 0, 0, 0);
      p0 = __builtin_amdgcn_mfma_f32_16x16x32_bf16(al, bh, p0, 0, 0, 0);
    }

    // ---- recurrent part
    if (t > 0) {
      const int t4 = t << 2;
      // all waves poll independently: 4 posts per producer WG per step
      if (lane < WPG) {
        while (__hip_atomic_load(&flags_g[lane * 16], __ATOMIC_RELAXED,
                                 __HIP_MEMORY_SCOPE_AGENT) < t4) { }
      }
      __builtin_amdgcn_fence(__ATOMIC_ACQUIRE, "agent");  // buffer_inv

      // batched A loads: 32 x 16B = 128 VGPR, single drain.
      // 16 base ptrs stride 4096B; imm offsets {0, 2048} (13-bit signed max 4095).
      const unsigned short* abase =
          th + grp_th + buf * (WPG * MT * NT) + mloc * NT + lk8;
      const unsigned short* bp[16];
      #pragma unroll
      for (int j = 0; j < 16; ++j) bp[j] = abase + j * 2 * (MT * NT);
      short8 A[32];
      #pragma unroll
      for (int c = 0; c < 32; ++c)
        LDA16(A[c], bp[c >> 1], (c & 1) * (MT * NT * 2));
      asm volatile("s_waitcnt vmcnt(0)" ::: "memory");
      __builtin_amdgcn_sched_barrier(0);

      #pragma unroll
      for (int c = 0; c < 32; c += 2) {
        short8 b0h = *(const short8*)(whp + c * 1024);
        short8 b0l = *(const short8*)(wlp + c * 1024);
        p0 = __builtin_amdgcn_mfma_f32_16x16x32_bf16(A[c], b0h, p0, 0, 0, 0);
        q0 = __builtin_amdgcn_mfma_f32_16x16x32_bf16(A[c], b0l, q0, 0, 0, 0);
        short8 b1h = *(const short8*)(whp + (c + 1) * 1024);
        short8 b1l = *(const short8*)(wlp + (c + 1) * 1024);
        p1 = __builtin_amdgcn_mfma_f32_16x16x32_bf16(A[c+1], b1h, p1, 0, 0, 0);
        q1 = __builtin_amdgcn_mfma_f32_16x16x32_bf16(A[c+1], b1l, q1, 0, 0, 0);
      }
    }

    // ---- epilogue: h, tanh, single-bf16 write-through publish (per wave)
    f32x4 hs = (p0 + p1) + (q0 + q1);
    const int nbuf = (t + 1) & 1;
    unsigned short* oh = th + grp_th + nbuf * (WPG * MT * NT) + gn * (MT * NT);
    float hout[4];
    #pragma unroll
    for (int r = 0; r < 4; ++r) {
      const int mr = msub * 16 + g4 * 4 + r;       // C-frag row (m89 layout)
      float h = hs[r] + nzv;
      hout[r] = h;
      float e  = __expf(2.f * h);
      float tv = 1.f - 2.f / (e + 1.f);            // tanh
      st_b16_sc1(oh + mr * NT + nloc, f2bf(tv));
    }
    asm volatile("s_waitcnt vmcnt(0)" ::: "memory");  // my th stores at MALL
    if (lane == 0)
      __hip_atomic_fetch_add(&flags_g[gn * 16], 1, __ATOMIC_RELAXED,
                             __HIP_MEMORY_SCOPE_AGENT);

    // ---- off the critical path: outputs + next-step x/noise prefetch
    #pragma unroll
    for (int r = 0; r < 4; ++r) {
      const int mr = msub * 16 + g4 * 4 + r;
      const int br = gm * MT + mr;
      if (br == BB - 1) out[(size_t)n_glob * TT + t] = hout[r];
      if (t == TT - 1)
        out[(size_t)NRECN * TT + (size_t)br * NRECN + n_glob] = hout[r];
    }
    if (t + 1 < TT) {
      const float* xp = xrow + (size_t)(t + 1) * NIN + lk8;
      xn0 = *(const f32x4*)xp;        xn1 = *(const f32x4*)(xp + 4);
      xn2 = *(const f32x4*)(xp + 32); xn3 = *(const f32x4*)(xp + 36);
      nzn = noise[(size_t)(t + 1) * NRECN + n_glob] * NOISE_STD;
    }
    xv0 = xn0; xv1 = xn1; xv2 = xn2; xv3 = xn3; nzv = nzn;
  }
}

extern "C" void kernel_launch(void* const* d_in, const int* in_sizes, int n_in,
                              void* d_out, int out_size, void* d_ws, size_t ws_size,
                              hipStream_t stream) {
  const float* x     = (const float*)d_in[0];
  const float* W_ih  = (const float*)d_in[1];
  const float* W_hh  = (const float*)d_in[2];
  const float* noise = (const float*)d_in[3];
  float* out = (float*)d_out;

  char* ws = (char*)d_ws;
  int* flags = (int*)ws;                                 // 64 counters, 64B apart
  unsigned short* th = (unsigned short*)(ws + 4096);     // [2][2][32][32][32] bf16
  // ws usage: 4096 + 2*2*32*32*32*2 = 266,240 bytes

  (void)hipMemsetAsync(flags, 0, 4096, stream);          // deterministic replays

  const size_t lds_bytes = (size_t)2 * KTOT * NT * sizeof(unsigned short); // 139,264
  (void)hipFuncSetAttribute((const void*)rnn_scan_kernel,
                            hipFuncAttributeMaxDynamicSharedMemorySize,
                            (int)lds_bytes);

  rnn_scan_kernel<<<dim3(NWG), dim3(256), lds_bytes, stream>>>(
      x, W_ih, W_hh, noise, out, flags, th);
}